// Round 15
// baseline (418.862 us; speedup 1.0000x reference)
//
#include <hip/hip_runtime.h>

// Problem constants (fixed by reference)
#define NVV 10000    // vertices
#define NKSTEPS 80   // 2560 / 32
#define KSPLIT 40    // ksteps per K-half
#define BN_INV 0.99950037468777316f

#define AS1 __attribute__((address_space(1)))

typedef float f32x4 __attribute__((ext_vector_type(4)));
typedef short short8 __attribute__((ext_vector_type(8)));
typedef unsigned short ushort;

// A chunk (LDS): [mt 5][sp 2][qk 4][mm 16][kk 8] ushort = 5120 ushorts = 10240 B
// A fragment (mt,sp) = contiguous 1024 B; lane i holds bytes [16i,16i+16).
#define ACH_USH 5120
// W chunk (per kstep,strip): [nt 8][sp 2][q 4][l16 16][kk 8] = 16384 B
#define WCH_B   16384

// ---------------------------------------------------------------------------
// Split a f32 into bf16 (RNE) + f32 remainder (exact).
__device__ __forceinline__ ushort bsplit(float v, float& rem) {
    unsigned u = __float_as_uint(v);
    unsigned r = (u + 0x7fffu + ((u >> 16) & 1u)) & 0xffff0000u;
    rem = v - __uint_as_float(r);
    return (ushort)(r >> 16);
}

// blend 3 gathered float4 rows, split-2 (RNE+RNE), store into A-frag layout
__device__ __forceinline__ void interp_store2(ushort* __restrict__ dstp, int it,
                                              const float4& g0, const float4& g1, const float4& g2,
                                              float w0, float w1, float w2) {
    const int m = it >> 3, kq = it & 7;
    const float av[4] = {g0.x, g0.y, g0.z, g0.w};
    const float bv[4] = {g1.x, g1.y, g1.z, g1.w};
    const float cv[4] = {g2.x, g2.y, g2.z, g2.w};
    ushort h1[4], h2[4];
    #pragma unroll
    for (int e = 0; e < 4; ++e) {
        const float vv = w0 * av[e] + w1 * bv[e] + w2 * cv[e];
        float r1, r2;
        h1[e] = bsplit(vv, r1); h2[e] = bsplit(r1, r2);
    }
    const int mt = m >> 4, mm = m & 15, qk = kq >> 1, hf = kq & 1;
    const int o0 = ((mt * 2 + 0) * 4 + qk) * 128 + mm * 8 + hf * 4;   // ushort units
    *(uint2*)(dstp + o0)       = make_uint2((unsigned)h1[0] | ((unsigned)h1[1] << 16),
                                            (unsigned)h1[2] | ((unsigned)h1[3] << 16));
    *(uint2*)(dstp + o0 + 512) = make_uint2((unsigned)h2[0] | ((unsigned)h2[1] << 16),
                                            (unsigned)h2[2] | ((unsigned)h2[3] << 16));
}

// ---------------------------------------------------------------------------
// W global layout (per stage): [kstep 80][strip 4] chunks of 16384 B.
// w = w1 + w2 (2 RNE planes; residual <= 2^-16 relative).
__global__ void build_w_kernel(const float* __restrict__ t1,
                               const float* __restrict__ t2,
                               ushort* __restrict__ W1g,
                               ushort* __restrict__ W2g) {
    const int k = blockIdx.x;       // 0..2559
    const int n = threadIdx.x;      // 0..511
    const float* T  = blockIdx.y ? t2 : t1;
    ushort*      Wg = blockIdx.y ? W2g : W1g;
    const int r = k >> 9, a = (k >> 6) & 7, c = k & 63;
    const int o = n >> 6, t = n & 63;
    const float w = T[((t * 5 + r) * 8 + ((o + a) & 7)) * 64 + c];
    float r1, r2;
    const ushort h1 = bsplit(w, r1);
    const ushort h2 = bsplit(r1, r2);
    const int kstep = k >> 5, kw = k & 31, q = kw >> 3, kk = kw & 7;
    const int strip = n >> 7, nl = n & 127, nt = nl >> 4, l16 = nl & 15;
    const size_t base = (size_t)(kstep * 4 + strip) * 8192;
    const int off = ((nt * 2 + 0) * 4 + q) * 128 + l16 * 8 + kk;
    Wg[base + off]       = h1;      // sp stride = 512 ushorts
    Wg[base + off + 512] = h2;
}

// ---------------------------------------------------------------------------
// FUSED interp + 3-product split MFMA GEMM. Full-N block = 80 rows x 512
// cols x K=1280 (KSPLIT=40); grid 250 = 125 mg x 2 khalf — every block
// resident (1/CU at ~290 VGPR). Since R12 each (mg,kstep) A-chunk has ONE
// consumer block, so interp is computed in-block (gathers+blend+split into
// a 2x10 KB LDS dbuf) — no A materialization, no HBM round-trip. W frags
// load direct-to-VGPR (dbuf) from the L2-resident 5.24 MB W. One barrier
// per kstep; gathers/W-loads issue at kstep start, drained ~800 cyc later.
#define GATHERS(KS)                                                         \
    _Pragma("unroll")                                                       \
    for (int s = 0; s < 3; ++s) {                                           \
        const int it = x + 256 * s;                                         \
        if (it < 640) {                                                     \
            const int m = it >> 3, kq = it & 7;                             \
            const int v = Mbase + m;                                        \
            const int ra = (KS) >> 1;                                       \
            const int*   ip = bc_idx + v * 120 + ra * 3;                    \
            const float* wp = bc_w  + v * 120 + ra * 3;                     \
            const int c0 = ((KS) & 1) * 32 + kq * 4;                        \
            ga[s] = *(const float4*)(src + (size_t)ip[0] * 64 + c0);        \
            gb[s] = *(const float4*)(src + (size_t)ip[1] * 64 + c0);        \
            gc[s] = *(const float4*)(src + (size_t)ip[2] * 64 + c0);        \
            wa[s] = wp[0]; wb[s] = wp[1]; wc[s] = wp[2];                    \
        }                                                                   \
    }

#define BLENDSTORE(DST)                                                     \
    _Pragma("unroll")                                                       \
    for (int s = 0; s < 3; ++s) {                                           \
        const int it = x + 256 * s;                                         \
        if (it < 640)                                                       \
            interp_store2((DST), it, ga[s], gb[s], gc[s], wa[s], wb[s], wc[s]); \
    }

#define WLOADS(WB, KS)                                                      \
    {                                                                       \
        const AS1 char* wn = wBase + (size_t)(KS) * (4 * WCH_B);            \
        _Pragma("unroll")                                                   \
        for (int f = 0; f < 16; ++f)                                        \
            WB[f] = *(const AS1 short8*)(wn + f * 1024);                    \
    }

#define GEMM_MFMAS(SAC, WB)                                                 \
    _Pragma("unroll")                                                       \
    for (int mt = 0; mt < 5; ++mt) {                                        \
        const short8 a1 = *(const short8*)((SAC) + (mt * 2 + 0) * 512 + lane * 8); \
        const short8 a2 = *(const short8*)((SAC) + (mt * 2 + 1) * 512 + lane * 8); \
        _Pragma("unroll")                                                   \
        for (int nt = 0; nt < 8; ++nt) {                                    \
            d[mt][nt] = __builtin_amdgcn_mfma_f32_16x16x32_bf16(            \
                a1, WB[nt * 2 + 0], d[mt][nt], 0, 0, 0);                    \
            d[mt][nt] = __builtin_amdgcn_mfma_f32_16x16x32_bf16(            \
                a1, WB[nt * 2 + 1], d[mt][nt], 0, 0, 0);                    \
            d[mt][nt] = __builtin_amdgcn_mfma_f32_16x16x32_bf16(            \
                a2, WB[nt * 2 + 0], d[mt][nt], 0, 0, 0);                    \
        }                                                                   \
    }

__global__ __launch_bounds__(256, 1)
void gemm_kernel(const float* __restrict__ src,      // gather source (rows of 64)
                 const int*   __restrict__ bc_idx,   // (V,R,A,3)
                 const float* __restrict__ bc_w,     // (V,R,A,3)
                 const ushort* __restrict__ Wg,
                 float*       __restrict__ S1,       // (V,512) partial, khalf 0
                 float*       __restrict__ S2) {     // (V,512) partial, khalf 1
    __shared__ ushort sA[2][ACH_USH];   // 2 x 10240 B interp chunk dbuf
    const int b = blockIdx.x;
    const int mgl   = b >> 1;
    const int khalf = b & 1;
    const int Mbase = mgl * 80;
    const int ks0   = khalf * KSPLIT;   // even
    const int ksend = ks0 + KSPLIT;
    const int x = threadIdx.x;
    const int wj   = x >> 6;            // wave -> strip
    const int lane = x & 63;
    const int l16  = lane & 15;
    const int q    = lane >> 4;

    f32x4 d[5][8] = {};                 // 160 f32 accumulators

    const AS1 char* wBase = (const AS1 char*)Wg + (size_t)wj * WCH_B + lane * 16;

    short8 W0[16], W1[16];
    float4 ga[3], gb[3], gc[3];
    float  wa[3], wb[3], wc[3];

    // ---- prologue: W(ks0) -> W0 (long latency first), interp(ks0) -> sA[0]
    WLOADS(W0, ks0);
    GATHERS(ks0);
    BLENDSTORE(sA[0]);
    __syncthreads();

    // ---- main loop: 2x unrolled, one barrier per kstep ----
    for (int ks = ks0; ks < ksend; ks += 2) {
        // step A: consume sA[0] + W0
        if (ks + 1 < ksend) { WLOADS(W1, ks + 1); GATHERS(ks + 1); }
        GEMM_MFMAS(sA[0], W0);
        if (ks + 1 < ksend) BLENDSTORE(sA[1]);
        __syncthreads();
        // step B: consume sA[1] + W1   (KSPLIT even -> always valid)
        if (ks + 2 < ksend) { WLOADS(W0, ks + 2); GATHERS(ks + 2); }
        GEMM_MFMAS(sA[1], W1);
        if (ks + 2 < ksend) BLENDSTORE(sA[0]);
        __syncthreads();
    }

    // ---- epilogue: store raw partial (no bias) to this half's S buffer ----
    float* Sh = khalf ? S2 : S1;
    #pragma unroll
    for (int mt = 0; mt < 5; ++mt) {
        #pragma unroll
        for (int nt = 0; nt < 8; ++nt) {
            #pragma unroll
            for (int r = 0; r < 4; ++r) {
                const int mglob = Mbase + mt * 16 + q * 4 + r;
                const int nglob = wj * 128 + nt * 16 + l16;
                Sh[(size_t)mglob * 512 + nglob] = d[mt][nt][r];
            }
        }
    }
}

// ---------------------------------------------------------------------------
// Combine partials + bias, angular max-pool + BN (+residual) + ReLU.
// One wave per vertex: lane = t, loop over the 8 o's; butterfly norm reduce.
template<bool RES>
__global__ void pool_kernel(const float* __restrict__ S1,
                            const float* __restrict__ S2,
                            const float* __restrict__ bias,
                            const float* __restrict__ gamma,
                            const float* __restrict__ beta,
                            const float* __restrict__ resid,
                            float*       __restrict__ dst) {
    const int w = threadIdx.x >> 6;           // wave 0..3
    const int t = threadIdx.x & 63;
    const int v = blockIdx.x * 4 + w;         // grid 2500 -> 10000 vertices
    const float bt = bias[t];
    float vals[8], n2[8];
    #pragma unroll
    for (int o = 0; o < 8; ++o) {
        const size_t idx = (size_t)v * 512 + o * 64 + t;
        const float val = S1[idx] + S2[idx] + bt;
        vals[o] = val;
        float s = val * val;
        #pragma unroll
        for (int off = 1; off < 64; off <<= 1) s += __shfl_xor(s, off, 64);
        n2[o] = s;
    }
    int bj = 0; float bv = n2[0];
    #pragma unroll
    for (int j = 1; j < 8; ++j) {
        if (n2[j] > bv) { bv = n2[j]; bj = j; }   // first-max tie-break (jnp.argmax)
    }
    float val = vals[0];
    #pragma unroll
    for (int j = 1; j < 8; ++j) val = (bj == j) ? vals[j] : val;
    float r = gamma[t] * (val * BN_INV) + beta[t];
    if (RES) r += resid[(size_t)v * 64 + t];
    dst[(size_t)v * 64 + t] = fmaxf(r, 0.0f);
}

// ---------------------------------------------------------------------------
extern "C" void kernel_launch(void* const* d_in, const int* in_sizes, int n_in,
                              void* d_out, int out_size, void* d_ws, size_t ws_size,
                              hipStream_t stream) {
    const float* signal = (const float*)d_in[0];
    const float* bc_w   = (const float*)d_in[1];
    const float* t1     = (const float*)d_in[2];
    const float* bias1  = (const float*)d_in[3];
    const float* gamma1 = (const float*)d_in[4];
    const float* beta1  = (const float*)d_in[5];
    const float* t2     = (const float*)d_in[6];
    const float* bias2  = (const float*)d_in[7];
    const float* gamma2 = (const float*)d_in[8];
    const float* beta2  = (const float*)d_in[9];
    const int*   bc_idx = (const int*)d_in[10];

    // ws: W1g 5.24 | W2g 5.24 | S1 20.48 | S2 20.48 | s1 2.56 MB  (~54 MB)
    const size_t WSTG = (size_t)NKSTEPS * 4 * 8192;       // ushorts per stage W
    ushort* W1g = (ushort*)d_ws;
    ushort* W2g = W1g + WSTG;
    float* S1 = (float*)(W2g + WSTG);
    float* S2 = S1 + (size_t)NVV * 512;
    float* s1 = S2 + (size_t)NVV * 512;
    float* out = (float*)d_out;

    build_w_kernel<<<dim3(2560, 2), 512, 0, stream>>>(t1, t2, W1g, W2g);

    gemm_kernel<<<250, 256, 0, stream>>>(signal, bc_idx, bc_w, W1g, S1, S2);
    pool_kernel<false><<<2500, 256, 0, stream>>>(S1, S2, bias1, gamma1, beta1, nullptr, s1);

    gemm_kernel<<<250, 256, 0, stream>>>(s1, bc_idx, bc_w, W2g, S1, S2);
    pool_kernel<true><<<2500, 256, 0, stream>>>(S1, S2, bias2, gamma2, beta2, signal, out);
}